// Round 3
// baseline (254.792 us; speedup 1.0000x reference)
//
#include <hip/hip_runtime.h>

#define B_DIM 1024
#define S_DIM 16
#define H_DIM 1024
#define N_DIM 16384
#define L_DIM 128
#define KX    (H_DIM + L_DIM)   // 1152, divisible by 64

typedef __bf16 bf16_8 __attribute__((ext_vector_type(8)));
typedef float  f32x4  __attribute__((ext_vector_type(4)));

// round-to-nearest-even f32 -> bf16 (bit trick; inputs finite)
__device__ __forceinline__ unsigned short f2bf(float f) {
    unsigned int u = __float_as_uint(f);
    u += 0x7fffu + ((u >> 16) & 1u);
    return (unsigned short)(u >> 16);
}

// async global -> LDS, 16 B per lane (dest must be uniform-base + lane*16)
#define GLD16(gp, lp)                                                          \
    __builtin_amdgcn_global_load_lds(                                          \
        (const __attribute__((address_space(1))) void*)(gp),                   \
        (__attribute__((address_space(3))) void*)(lp), 16, 0, 0)

// ---------------------------------------------------------------------------
// Kernel 1: label aggregation + build bf16 GEMM input row [cls | agg].
// Transposed bins: binsT[label][column], column = t&63. Atomic address =
// label*64 + c -> bank = c%32: ALWAYS 2 lanes/bank (free), independent of
// label values. (Rounds 1-2 showed label-dependent banking serializes the
// LDS atomic pipe at ~211 cyc/wave-op regardless of bin-copy count.)
// ---------------------------------------------------------------------------
__global__ __launch_bounds__(256) void k_agg(
    const float* __restrict__ feats,   // (B, S, H)
    const float* __restrict__ sims,    // (B, N)
    const int*   __restrict__ labels,  // (B, N)
    unsigned short* __restrict__ xin)  // (B, KX) bf16
{
    __shared__ float binsT[L_DIM][64];  // 32 KB -> 4 blocks/CU (grid-limited)
    const int b = blockIdx.x;
    const int t = threadIdx.x;
    const int c = t & 63;               // per-lane column -> bank = c%32

    float* flat = (float*)binsT;
    #pragma unroll
    for (int i = 0; i < L_DIM * 64 / 256; ++i) flat[t + i * 256] = 0.f;
    __syncthreads();

    const float4* s4 = (const float4*)(sims   + (size_t)b * N_DIM);
    const int4*   l4 = (const int4*)  (labels + (size_t)b * N_DIM);
    #pragma unroll 4
    for (int v = t; v < N_DIM / 4; v += 256) {
        float4 s  = s4[v];
        int4   li = l4[v];
        atomicAdd(&binsT[li.x][c], s.x);
        atomicAdd(&binsT[li.y][c], s.y);
        atomicAdd(&binsT[li.z][c], s.z);
        atomicAdd(&binsT[li.w][c], s.w);
    }
    __syncthreads();

    unsigned short* xrow = xin + (size_t)b * KX;
    // cls = features[b, 0, :]: 1024 floats, one float4 per thread
    const float4* c4 = (const float4*)(feats + (size_t)b * (S_DIM * H_DIM));
    float4 cv = c4[t];
    ushort4 p;
    p.x = f2bf(cv.x); p.y = f2bf(cv.y); p.z = f2bf(cv.z); p.w = f2bf(cv.w);
    *(ushort4*)(xrow + t * 4) = p;

    if (t < L_DIM) {
        float s = 0.f;
        #pragma unroll
        for (int i = 0; i < 64; ++i) s += binsT[t][(i + t) & 63]; // skewed: 2/bank
        xrow[H_DIM + t] = f2bf(s * (1.0f / N_DIM));
    }
}

// ---------------------------------------------------------------------------
// Kernel 2: f32 -> bf16 conversion of both weight matrices (grid-stride)
// ---------------------------------------------------------------------------
__global__ __launch_bounds__(256) void k_cvt(
    const float* __restrict__ w1, const float* __restrict__ w2,
    unsigned short* __restrict__ o1, unsigned short* __restrict__ o2,
    int n1v, int n2v)  // counts in float4 units
{
    int idx = blockIdx.x * 256 + threadIdx.x;
    int stride = gridDim.x * 256;
    for (int i = idx; i < n1v + n2v; i += stride) {
        const float4* src; unsigned short* dst; int j;
        if (i < n1v) { src = (const float4*)w1; dst = o1; j = i; }
        else         { src = (const float4*)w2; dst = o2; j = i - n1v; }
        float4 v = src[j];
        ushort4 p;
        p.x = f2bf(v.x); p.y = f2bf(v.y); p.z = f2bf(v.z); p.w = f2bf(v.w);
        *(ushort4*)(dst + j * 4) = p;
    }
}

// ---------------------------------------------------------------------------
// bf16 MFMA GEMM, C = A(MxK) . B(NxK)^T, both row-major, K contiguous.
// 64x32 tile (BM=64, BN=32), BK=64, 4 waves: wave (wm,wn) owns 32x16
// (2x1 frags of 16x16x32). Smaller tile -> 2x more blocks -> 2 blocks/CU
// (2 waves/SIMD) for TLP latency hiding that the 1-block/CU 64x64 lacked.
// Staging: global_load_lds 16B, XOR-swizzled SOURCE granule (g ^= row&7),
// linear LDS dest + swizzled ds_read (G21 both-sides) -> conflict-free b128.
// Pipeline: 3 LDS buffers, 2-deep prefetch, counted vmcnt (never 0 mid-loop).
// EPI=0: bias+tanh -> bf16; EPI=1: bias -> f32.
// ---------------------------------------------------------------------------
template <int EPI>
__global__ __launch_bounds__(256) void k_gemm_bt(
    const unsigned short* __restrict__ A,   // M x K bf16
    const unsigned short* __restrict__ Bm,  // N x K bf16
    const float* __restrict__ bias,         // N
    void* __restrict__ Cout,
    int M, int N, int K, int ldc)
{
    __shared__ __align__(16) unsigned short smA[3][64 * 64];  // 24 KB
    __shared__ __align__(16) unsigned short smB[3][32 * 64];  // 12 KB

    const int t    = threadIdx.x;
    const int lane = t & 63;
    const int w    = t >> 6;
    const int wm   = w >> 1, wn = w & 1;
    const int m0   = blockIdx.y * 64;
    const int n0   = blockIdx.x * 32;
    const int lr   = lane & 15;
    const int hi   = lane >> 4;

    // pre-swizzled global source offsets (elements)
    int srcA[2];
    #pragma unroll
    for (int j = 0; j < 2; ++j) {
        int li  = t + j * 256;          // A granule 0..511
        int row = li >> 3;
        int g   = (li & 7) ^ (row & 7);
        srcA[j] = row * K + g * 8;
    }
    const int rowB = t >> 3;            // B granule 0..255
    const int gB   = (t & 7) ^ (rowB & 7);
    const int srcB = rowB * K + gB * 8;

    const size_t aBase = (size_t)m0 * K;
    const size_t bBase = (size_t)n0 * K;

    const int nt = K >> 6;
    f32x4 acc[2] = {};

#define STAGE(buf, k0_)                                                        \
    do {                                                                       \
        GLD16(Bm + bBase + (size_t)(srcB + (k0_)), &smB[buf][t * 8]);          \
        _Pragma("unroll")                                                      \
        for (int j = 0; j < 2; ++j) {                                          \
            int li = t + j * 256;                                              \
            GLD16(A + aBase + (size_t)(srcA[j] + (k0_)), &smA[buf][li * 8]);   \
        }                                                                      \
    } while (0)

    STAGE(0, 0);
    if (nt > 1) STAGE(1, 64);

    int cur = 0;
    for (int ti = 0; ti < nt; ++ti) {
        int b2 = cur + 2; if (b2 >= 3) b2 -= 3;
        if (ti + 2 < nt) {
            STAGE(b2, (ti + 2) << 6);
            asm volatile("s_waitcnt vmcnt(6)" ::: "memory");
        } else if (ti + 1 < nt) {
            asm volatile("s_waitcnt vmcnt(3)" ::: "memory");
        } else {
            asm volatile("s_waitcnt vmcnt(0)" ::: "memory");
        }
        __builtin_amdgcn_s_barrier();
        asm volatile("" ::: "memory");

        const unsigned short* As = smA[cur];
        const unsigned short* Bs = smB[cur];
        #pragma unroll
        for (int ks = 0; ks < 2; ++ks) {
            const int gl = ks * 4 + hi;               // logical granule
            const int ga = (gl ^ (lr & 7)) * 8;       // swizzled elem offset
            bf16_8 a0 = *(const bf16_8*)(As + (wm * 32 +      lr) * 64 + ga);
            bf16_8 a1 = *(const bf16_8*)(As + (wm * 32 + 16 + lr) * 64 + ga);
            bf16_8 b0 = *(const bf16_8*)(Bs + (wn * 16 +      lr) * 64 + ga);
            acc[0] = __builtin_amdgcn_mfma_f32_16x16x32_bf16(a0, b0, acc[0], 0, 0, 0);
            acc[1] = __builtin_amdgcn_mfma_f32_16x16x32_bf16(a1, b0, acc[1], 0, 0, 0);
        }

        asm volatile("" ::: "memory");
        __builtin_amdgcn_s_barrier();
        cur = cur + 1; if (cur >= 3) cur = 0;
    }

    // epilogue: C/D layout col = lane&15, row = (lane>>4)*4 + reg  [m89]
    const int rbase = m0 + wm * 32 + hi * 4;
    const int col   = n0 + wn * 16 + lr;
    const float bv  = bias[col];
    #pragma unroll
    for (int i = 0; i < 2; ++i) {
        #pragma unroll
        for (int r = 0; r < 4; ++r) {
            int row = rbase + i * 16 + r;
            float v = acc[i][r] + bv;
            if (EPI == 0) {
                v = tanhf(v);
                ((unsigned short*)Cout)[(size_t)row * ldc + col] = f2bf(v);
            } else {
                ((float*)Cout)[(size_t)row * ldc + col] = v;
            }
        }
    }
#undef STAGE
}

// ---------------------------------------------------------------------------
extern "C" void kernel_launch(void* const* d_in, const int* in_sizes, int n_in,
                              void* d_out, int out_size, void* d_ws, size_t ws_size,
                              hipStream_t stream) {
    const float* feats   = (const float*)d_in[0];
    const float* sims    = (const float*)d_in[1];
    const int*   labels  = (const int*)  d_in[2];
    const float* dense_w = (const float*)d_in[3];
    const float* dense_b = (const float*)d_in[4];
    const float* out_w   = (const float*)d_in[5];
    const float* out_b   = (const float*)d_in[6];
    float* out = (float*)d_out;

    // workspace layout (bf16 buffers), total ~7.1 MB
    unsigned short* xin  = (unsigned short*)d_ws;               // B x KX
    unsigned short* wd   = xin  + (size_t)B_DIM * KX;           // H x KX
    unsigned short* wo   = wd   + (size_t)H_DIM * KX;           // L x H
    unsigned short* xmid = wo   + (size_t)L_DIM * H_DIM;        // B x H

    k_agg<<<B_DIM, 256, 0, stream>>>(feats, sims, labels, xin);

    int n1v = (H_DIM * KX) / 4;
    int n2v = (L_DIM * H_DIM) / 4;
    k_cvt<<<512, 256, 0, stream>>>(dense_w, out_w, wd, wo, n1v, n2v);

    dim3 g1(H_DIM / 32, B_DIM / 64);   // (32, 16) = 512 blocks
    k_gemm_bt<0><<<g1, 256, 0, stream>>>(xin, wd, dense_b, (void*)xmid,
                                         B_DIM, H_DIM, KX, H_DIM);

    dim3 g2(L_DIM / 32, B_DIM / 64);   // (4, 16) = 64 blocks
    k_gemm_bt<1><<<g2, 256, 0, stream>>>(xmid, wo, out_b, (void*)out,
                                         B_DIM, L_DIM, H_DIM, L_DIM);
}

// Round 6
// 224.914 us; speedup vs baseline: 1.1328x; 1.1328x over previous
//
#include <hip/hip_runtime.h>

#define B_DIM 1024
#define S_DIM 16
#define H_DIM 1024
#define N_DIM 16384
#define L_DIM 128
#define KX    (H_DIM + L_DIM)   // 1152, divisible by 64

typedef __bf16 bf16_8 __attribute__((ext_vector_type(8)));
typedef float  f32x4  __attribute__((ext_vector_type(4)));

// round-to-nearest-even f32 -> bf16 (bit trick; inputs finite)
__device__ __forceinline__ unsigned short f2bf(float f) {
    unsigned int u = __float_as_uint(f);
    u += 0x7fffu + ((u >> 16) & 1u);
    return (unsigned short)(u >> 16);
}

// async global -> LDS, 16 B per lane (dest must be uniform-base + lane*16)
#define GLD16(gp, lp)                                                          \
    __builtin_amdgcn_global_load_lds(                                          \
        (const __attribute__((address_space(1))) void*)(gp),                   \
        (__attribute__((address_space(3))) void*)(lp), 16, 0, 0)

// ---------------------------------------------------------------------------
// Kernel 1: label aggregation, ATOMIC-FREE. Rounds 1-3 proved LDS atomics
// cost ~211 cyc/wave-op regardless of banking. Here: 1 wave/block, each lane
// owns private column c of binsT[129][64] -> plain ds_read+add+ds_write
// (LDS is in-order per wave). Duplicate labels inside a float4 are merged
// in-register and redirected to dummy row 128 (carrying 0), so the 4 RMWs
// of a group are alias-free-or-harmless. Bank = c%32: 2 lanes/bank, free.
// ---------------------------------------------------------------------------
__global__ __launch_bounds__(64) void k_agg(
    const float* __restrict__ feats,   // (B, S, H)
    const float* __restrict__ sims,    // (B, N)
    const int*   __restrict__ labels,  // (B, N)
    unsigned short* __restrict__ xin)  // (B, KX) bf16
{
    __shared__ float bins[129 * 64];   // 33 KB -> 4 blocks/CU
    const int bb = blockIdx.x;
    const int t  = threadIdx.x;        // 0..63 == private column

    #pragma unroll
    for (int i = 0; i < 129; ++i) bins[i * 64 + t] = 0.f;
    __syncthreads();

    const float4* s4 = (const float4*)(sims   + (size_t)bb * N_DIM);
    const int4*   l4 = (const int4*)  (labels + (size_t)bb * N_DIM);

    float4 fs[2][4];
    int4   fl[2][4];

#define LOADB(slot, bt)                                                        \
    do {                                                                       \
        _Pragma("unroll")                                                      \
        for (int q = 0; q < 4; ++q) {                                          \
            fs[slot][q] = s4[((bt) * 4 + q) * 64 + t];                         \
            fl[slot][q] = l4[((bt) * 4 + q) * 64 + t];                         \
        }                                                                      \
    } while (0)

#define UPD4(sv, lv)                                                           \
    do {                                                                       \
        int   l0 = (lv).x, l1 = (lv).y, l2 = (lv).z, l3 = (lv).w;              \
        float v0 = (sv).x, v1 = (sv).y, v2 = (sv).z, v3 = (sv).w;              \
        if (l1 == l0) { v0 += v1; v1 = 0.f; l1 = 128; }                        \
        if (l2 == l0) { v0 += v2; v2 = 0.f; l2 = 128; }                        \
        if (l3 == l0) { v0 += v3; v3 = 0.f; l3 = 128; }                        \
        if (l2 == l1) { v1 += v2; v2 = 0.f; l2 = 128; }                        \
        if (l3 == l1) { v1 += v3; v3 = 0.f; l3 = 128; }                        \
        if (l3 == l2) { v2 += v3; v3 = 0.f; l3 = 128; }                        \
        float* p0 = &bins[l0 * 64 + t];                                        \
        float* p1 = &bins[l1 * 64 + t];                                        \
        float* p2 = &bins[l2 * 64 + t];                                        \
        float* p3 = &bins[l3 * 64 + t];                                        \
        float r0 = *p0, r1 = *p1, r2 = *p2, r3 = *p3;                          \
        *p0 = r0 + v0; *p1 = r1 + v1; *p2 = r2 + v2; *p3 = r3 + v3;            \
    } while (0)

    LOADB(0, 0);
    LOADB(1, 1);
    #pragma unroll
    for (int bt = 0; bt < 16; ++bt) {
        const int sl = bt & 1;
        #pragma unroll
        for (int q = 0; q < 4; ++q) UPD4(fs[sl][q], fl[sl][q]);
        if (bt + 2 < 16) LOADB(sl, bt + 2);
    }
    __syncthreads();

    unsigned short* xrow = xin + (size_t)bb * KX;
    // cls = features[bb, 0, :]: 1024 floats = 256 float4, 4 per lane
    const float4* c4 = (const float4*)(feats + (size_t)bb * (S_DIM * H_DIM));
    #pragma unroll
    for (int i = 0; i < 4; ++i) {
        float4 cv = c4[t + i * 64];
        ushort4 p;
        p.x = f2bf(cv.x); p.y = f2bf(cv.y); p.z = f2bf(cv.z); p.w = f2bf(cv.w);
        *(ushort4*)(xrow + (t + i * 64) * 4) = p;
    }

    // reduce 64 columns per bin; lane handles bins t and t+64; skewed banks
    #pragma unroll
    for (int pb = 0; pb < 2; ++pb) {
        const int l = pb * 64 + t;
        float a0 = 0.f, a1 = 0.f, a2 = 0.f, a3 = 0.f;
        #pragma unroll
        for (int i = 0; i < 64; i += 4) {
            a0 += bins[l * 64 + ((t + i)     & 63)];
            a1 += bins[l * 64 + ((t + i + 1) & 63)];
            a2 += bins[l * 64 + ((t + i + 2) & 63)];
            a3 += bins[l * 64 + ((t + i + 3) & 63)];
        }
        xrow[H_DIM + l] = f2bf((a0 + a1 + a2 + a3) * (1.0f / N_DIM));
    }
#undef LOADB
#undef UPD4
}

// ---------------------------------------------------------------------------
// Kernel 2: f32 -> bf16 conversion of both weight matrices (grid-stride)
// ---------------------------------------------------------------------------
__global__ __launch_bounds__(256) void k_cvt(
    const float* __restrict__ w1, const float* __restrict__ w2,
    unsigned short* __restrict__ o1, unsigned short* __restrict__ o2,
    int n1v, int n2v)  // counts in float4 units
{
    int idx = blockIdx.x * 256 + threadIdx.x;
    int stride = gridDim.x * 256;
    for (int i = idx; i < n1v + n2v; i += stride) {
        const float4* src; unsigned short* dst; int j;
        if (i < n1v) { src = (const float4*)w1; dst = o1; j = i; }
        else         { src = (const float4*)w2; dst = o2; j = i - n1v; }
        float4 v = src[j];
        ushort4 p;
        p.x = f2bf(v.x); p.y = f2bf(v.y); p.z = f2bf(v.z); p.w = f2bf(v.w);
        *(ushort4*)(dst + j * 4) = p;
    }
}

// ---------------------------------------------------------------------------
// bf16 MFMA GEMM, C = A(MxK) . B(NxK)^T, both row-major, K contiguous.
// 128x64 tile, BK=64, 4 waves: wave w owns rows [w*32, w*32+32) x 64 cols
// = 2x4 frags of 16x16x32 -> 16 MFMA + 12 ds_read_b128 per K-step (4x the
// MFMA-per-barrier of rounds 1-3, which delivered only ~15 TF).
// Staging: global_load_lds 16B, XOR-swizzled SOURCE granule (g ^= row&7),
// linear LDS dest + swizzled ds_read (G21 both-sides) -> conflict-free b128.
// Pipeline: 3 LDS buffers, 2-deep prefetch, counted vmcnt (never 0 mid-loop).
// EPI=0: bias+tanh -> bf16; EPI=1: bias -> f32.
// ---------------------------------------------------------------------------
template <int EPI>
__global__ __launch_bounds__(256) void k_gemm(
    const unsigned short* __restrict__ A,   // M x K bf16
    const unsigned short* __restrict__ Bm,  // N x K bf16
    const float* __restrict__ bias,         // N
    void* __restrict__ Cout,
    int M, int N, int K, int ldc)
{
    __shared__ __align__(16) unsigned short smA[3][128 * 64];  // 48 KB
    __shared__ __align__(16) unsigned short smB[3][64 * 64];   // 24 KB

    const int t    = threadIdx.x;
    const int lane = t & 63;
    const int w    = t >> 6;
    const int m0   = blockIdx.y * 128;
    const int n0   = blockIdx.x * 64;
    const int lr   = lane & 15;
    const int hi   = lane >> 4;
    const int sw   = lr & 7;          // per-lane read swizzle

    // pre-swizzled global source offsets (elements)
    int srcA[4], srcB[2];
    #pragma unroll
    for (int j = 0; j < 4; ++j) {
        int idx = t + j * 256;              // A granule 0..1023
        int row = idx >> 3;
        int g   = (idx & 7) ^ (row & 7);
        srcA[j] = row * K + g * 8;
    }
    #pragma unroll
    for (int j = 0; j < 2; ++j) {
        int idx = t + j * 256;              // B granule 0..511
        int row = idx >> 3;
        int g   = (idx & 7) ^ (row & 7);
        srcB[j] = row * K + g * 8;
    }
    const size_t aBase = (size_t)m0 * K;
    const size_t bBase = (size_t)n0 * K;

    const int nt = K >> 6;
    f32x4 acc[2][4] = {};

#define STAGE(buf, k0_)                                                        \
    do {                                                                       \
        _Pragma("unroll")                                                      \
        for (int j = 0; j < 4; ++j)                                            \
            GLD16(A + aBase + (size_t)(srcA[j] + (k0_)),                       \
                  &smA[buf][(t + j * 256) * 8]);                               \
        _Pragma("unroll")                                                      \
        for (int j = 0; j < 2; ++j)                                            \
            GLD16(Bm + bBase + (size_t)(srcB[j] + (k0_)),                      \
                  &smB[buf][(t + j * 256) * 8]);                               \
    } while (0)

    STAGE(0, 0);
    if (nt > 1) STAGE(1, 64);

    int cur = 0;
    for (int ti = 0; ti < nt; ++ti) {
        int b2 = cur + 2; if (b2 >= 3) b2 -= 3;
        if (ti + 2 < nt) {
            STAGE(b2, (ti + 2) << 6);
            asm volatile("s_waitcnt vmcnt(12)" ::: "memory");
        } else if (ti + 1 < nt) {
            asm volatile("s_waitcnt vmcnt(6)" ::: "memory");
        } else {
            asm volatile("s_waitcnt vmcnt(0)" ::: "memory");
        }
        __builtin_amdgcn_s_barrier();
        asm volatile("" ::: "memory");

        const unsigned short* As = smA[cur];
        const unsigned short* Bs = smB[cur];
        #pragma unroll
        for (int ks = 0; ks < 2; ++ks) {
            const int ga = ((ks * 4 + hi) ^ sw) * 8;   // swizzled elem offset
            bf16_8 a0 = *(const bf16_8*)(As + (w * 32 +      lr) * 64 + ga);
            bf16_8 a1 = *(const bf16_8*)(As + (w * 32 + 16 + lr) * 64 + ga);
            bf16_8 b0 = *(const bf16_8*)(Bs + (      lr) * 64 + ga);
            bf16_8 b1 = *(const bf16_8*)(Bs + (16  + lr) * 64 + ga);
            bf16_8 b2v = *(const bf16_8*)(Bs + (32 + lr) * 64 + ga);
            bf16_8 b3 = *(const bf16_8*)(Bs + (48  + lr) * 64 + ga);
            acc[0][0] = __builtin_amdgcn_mfma_f32_16x16x32_bf16(a0, b0,  acc[0][0], 0, 0, 0);
            acc[1][0] = __builtin_amdgcn_mfma_f32_16x16x32_bf16(a1, b0,  acc[1][0], 0, 0, 0);
            acc[0][1] = __builtin_amdgcn_mfma_f32_16x16x32_bf16(a0, b1,  acc[0][1], 0, 0, 0);
            acc[1][1] = __builtin_amdgcn_mfma_f32_16x16x32_bf16(a1, b1,  acc[1][1], 0, 0, 0);
            acc[0][2] = __builtin_amdgcn_mfma_f32_16x16x32_bf16(a0, b2v, acc[0][2], 0, 0, 0);
            acc[1][2] = __builtin_amdgcn_mfma_f32_16x16x32_bf16(a1, b2v, acc[1][2], 0, 0, 0);
            acc[0][3] = __builtin_amdgcn_mfma_f32_16x16x32_bf16(a0, b3,  acc[0][3], 0, 0, 0);
            acc[1][3] = __builtin_amdgcn_mfma_f32_16x16x32_bf16(a1, b3,  acc[1][3], 0, 0, 0);
        }

        asm volatile("" ::: "memory");
        __builtin_amdgcn_s_barrier();
        cur = cur + 1; if (cur >= 3) cur = 0;
    }

    // epilogue: C/D layout col = lane&15, row = (lane>>4)*4 + reg  [m89]
    const int rbase = m0 + w * 32 + hi * 4;
    const int cbase = n0 + lr;
    #pragma unroll
    for (int i = 0; i < 2; ++i) {
        #pragma unroll
        for (int j = 0; j < 4; ++j) {
            int col = cbase + j * 16;
            float bv = bias[col];
            #pragma unroll
            for (int r = 0; r < 4; ++r) {
                int row = rbase + i * 16 + r;
                float v = acc[i][j][r] + bv;
                if (EPI == 0) {
                    v = tanhf(v);
                    ((unsigned short*)Cout)[(size_t)row * ldc + col] = f2bf(v);
                } else {
                    ((float*)Cout)[(size_t)row * ldc + col] = v;
                }
            }
        }
    }
#undef STAGE
}

// ---------------------------------------------------------------------------
extern "C" void kernel_launch(void* const* d_in, const int* in_sizes, int n_in,
                              void* d_out, int out_size, void* d_ws, size_t ws_size,
                              hipStream_t stream) {
    const float* feats   = (const float*)d_in[0];
    const float* sims    = (const float*)d_in[1];
    const int*   labels  = (const int*)  d_in[2];
    const float* dense_w = (const float*)d_in[3];
    const float* dense_b = (const float*)d_in[4];
    const float* out_w   = (const float*)d_in[5];
    const float* out_b   = (const float*)d_in[6];
    float* out = (float*)d_out;

    // workspace layout (bf16 buffers), total ~7.1 MB
    unsigned short* xin  = (unsigned short*)d_ws;               // B x KX
    unsigned short* wd   = xin  + (size_t)B_DIM * KX;           // H x KX
    unsigned short* wo   = wd   + (size_t)H_DIM * KX;           // L x H
    unsigned short* xmid = wo   + (size_t)L_DIM * H_DIM;        // B x H

    k_agg<<<B_DIM, 64, 0, stream>>>(feats, sims, labels, xin);

    int n1v = (H_DIM * KX) / 4;
    int n2v = (L_DIM * H_DIM) / 4;
    k_cvt<<<512, 256, 0, stream>>>(dense_w, out_w, wd, wo, n1v, n2v);

    dim3 g1(H_DIM / 64, B_DIM / 128);   // (16, 8) = 128 blocks
    k_gemm<0><<<g1, 256, 0, stream>>>(xin, wd, dense_b, (void*)xmid,
                                      B_DIM, H_DIM, KX, H_DIM);

    dim3 g2(L_DIM / 64, B_DIM / 128);   // (2, 8) = 16 blocks
    k_gemm<1><<<g2, 256, 0, stream>>>(xmid, wo, out_b, (void*)out,
                                      B_DIM, L_DIM, H_DIM, L_DIM);
}